// Round 4
// baseline (42.216 us; speedup 1.0000x reference)
//
#include <hip/hip_runtime.h>

#define BB 16
#define CC 64
#define HH 64
#define WW 64
#define OO 128
#define HALO 6                       // 4 output rows + 1 halo row each side
#define LDS_BYTES (CC * HALO * WW * 4)   // 98304 B

// lane L (within a 16-lane DPP row) gets src from lane L-1; first lane keeps edge.
__device__ __forceinline__ float dpp_shr1(float src, float edge) {
    int old = __builtin_bit_cast(int, edge);
    int s   = __builtin_bit_cast(int, src);
    int r = __builtin_amdgcn_update_dpp(old, s, 0x111, 0xF, 0xF, false); // row_shr:1
    return __builtin_bit_cast(float, r);
}
// lane L gets src from lane L+1; last lane of each 16-lane row keeps edge.
__device__ __forceinline__ float dpp_shl1(float src, float edge) {
    int old = __builtin_bit_cast(int, edge);
    int s   = __builtin_bit_cast(int, src);
    int r = __builtin_amdgcn_update_dpp(old, s, 0x101, 0xF, 0xF, false); // row_shl:1
    return __builtin_bit_cast(float, r);
}

// Block: 512 threads = 8 waves. Wave = o_sub (o stays WAVE-UNIFORM -> s_load taps).
// Lane = row(0..3) * 16 + L(0..15); lane owns cols 4L..4L+3 of output row r0+row.
// LDS: full channel slab for a 4-row strip: xs[c][rl][col], rl = image rows
// r0-1 .. r0+4 clamped (replicate pad). 96 KB -> 1 block/CU, 2 waves/SIMD.
// Grid: 256 blocks = (b, row-quad) = exactly 1 per CU.
extern "C" __global__ __launch_bounds__(512, 1) void minimax_conv_kernel(
    const float* __restrict__ x, const float* __restrict__ w1,
    const float* __restrict__ w2, const int* __restrict__ conn,
    float* __restrict__ out)
{
    extern __shared__ float xs[];    // CC*HALO*WW floats

    const int tid = threadIdx.x;
    const int bid = blockIdx.x;
    const int b  = bid >> 4;
    const int r0 = (bid & 15) * 4;

    const float* xb = x + (size_t)b * (CC * HH * WW);

    // ---- stage slab: 24576 dwords = 12 rounds x 512 threads x float4 ----
    #pragma unroll
    for (int rnd = 0; rnd < 12; ++rnd) {
        const int f   = rnd * 512 + tid;       // 16-B chunk id, linear in LDS
        const int c   = f / 96;                // 96 chunks per channel
        const int rem = f * 4 - c * (HALO * WW); // dword remainder 0..383
        const int rl  = rem >> 6;              // 0..5
        const int col = rem & 63;              // multiple of 4
        int rimg = r0 - 1 + rl;
        rimg = rimg < 0 ? 0 : (rimg > HH - 1 ? HH - 1 : rimg);
        const float4 v = *(const float4*)(xb + (c * HH + rimg) * WW + col);
        *(float4*)(xs + f * 4) = v;
    }
    __syncthreads();

    const int lane = tid & 63;
    const int row  = lane >> 4;
    const int L    = lane & 15;
    const int osub = __builtin_amdgcn_readfirstlane(tid >> 6);  // 0..7, uniform

    // per-lane LDS dword offsets within a channel for kernel row i=0,1,2
    const int ro0 = (row + 0) * WW + 4 * L;
    const int ro1 = (row + 1) * WW + 4 * L;
    const int ro2 = (row + 2) * WW + 4 * L;

    #pragma unroll 2
    for (int oo = 0; oo < 16; ++oo) {
        const int o = oo * 8 + osub;           // wave-uniform

        float res0, res1, res2, res3;
        #pragma unroll
        for (int p = 0; p < 3; ++p) {
            float e0, e1, e2, e3;
            #pragma unroll
            for (int tt = 0; tt < 3; ++tt) {
                const int t = p * 3 + tt;
                const int v = conn[o * 9 + t];          // s_load (uniform)
                const int c = v / 9;
                const int rr = v - c * 9;
                const int i = rr / 3;                   // kernel row (uniform)
                const int j = rr - i * 3;               // kernel col (uniform)
                const float w1v = w1[o * 9 + t];        // uniform

                const int ro = (i == 0) ? ro0 : ((i == 1) ? ro1 : ro2);
                const float4 q = *(const float4*)(xs + c * (HALO * WW) + ro);

                float v0, v1, v2, v3;
                if (j == 0) {                           // uniform branch
                    const float le = dpp_shr1(q.w, q.x);
                    v0 = le;  v1 = q.x; v2 = q.y; v3 = q.z;
                } else if (j == 1) {
                    v0 = q.x; v1 = q.y; v2 = q.z; v3 = q.w;
                } else {
                    const float re = dpp_shl1(q.x, q.w);
                    v0 = q.y; v1 = q.z; v2 = q.w; v3 = re;
                }
                const float d0 = fabsf(v0 - w1v);
                const float d1 = fabsf(v1 - w1v);
                const float d2 = fabsf(v2 - w1v);
                const float d3 = fabsf(v3 - w1v);
                if (tt == 0) { e0 = d0; e1 = d1; e2 = d2; e3 = d3; }
                else {
                    e0 = fmaxf(e0, d0); e1 = fmaxf(e1, d1);
                    e2 = fmaxf(e2, d2); e3 = fmaxf(e3, d3);
                }
            }
            const float w2v = w2[o * 3 + p];            // uniform
            const float m0 = fabsf(e0 - w2v);
            const float m1 = fabsf(e1 - w2v);
            const float m2 = fabsf(e2 - w2v);
            const float m3 = fabsf(e3 - w2v);
            if (p == 0) { res0 = m0; res1 = m1; res2 = m2; res3 = m3; }
            else {
                res0 = fminf(res0, m0); res1 = fminf(res1, m1);
                res2 = fminf(res2, m2); res3 = fminf(res3, m3);
            }
        }

        float4 outv; outv.x = res0; outv.y = res1; outv.z = res2; outv.w = res3;
        *(float4*)(out + (((size_t)b * OO + o) * HH + (r0 + row)) * WW + 4 * L) = outv;
    }
}

extern "C" void kernel_launch(void* const* d_in, const int* in_sizes, int n_in,
                              void* d_out, int out_size, void* d_ws, size_t ws_size,
                              hipStream_t stream) {
    const float* x    = (const float*)d_in[0];
    const float* w1   = (const float*)d_in[1];
    const float* w2   = (const float*)d_in[2];
    const int*   conn = (const int*)d_in[3];
    float* out = (float*)d_out;

    // allow >64 KB dynamic LDS (96 KB slab); idempotent host call
    hipFuncSetAttribute((const void*)minimax_conv_kernel,
                        hipFuncAttributeMaxDynamicSharedMemorySize, LDS_BYTES);

    const int blocks = BB * 16;   // (b, row-quad) = 256 = 1 per CU
    minimax_conv_kernel<<<blocks, 512, LDS_BYTES, stream>>>(x, w1, w2, conn, out);
}

// Round 5
// 36.809 us; speedup vs baseline: 1.1469x; 1.1469x over previous
//
#include <hip/hip_runtime.h>

#define BB 16
#define CC 64
#define HH 64
#define WW 64
#define OO 128
#define HALO 6                            // 4 output rows + 1 halo row each side
#define SLAB_DW (CC * HALO * WW)          // 24576 dwords
#define LDS_BYTES (SLAB_DW * 4)           // 98304 B

// Block: 1024 threads = 16 waves (4/SIMD). One wave = one output ROW of one o:
// 64 lanes = 64 columns -> every LDS tap read is 64 consecutive dwords
// (conflict-free by construction; edge clamp = same-addr broadcast).
// Each task processes a ROW PAIR via xs[base] / xs[base+64] -> ds_read2_b32.
// LDS slab: xs[c][rl][col], rl = clamped image rows r0-1 .. r0+4 (96 KB).
// Grid: 256 blocks = (b, 4-row strip) = exactly 1 per CU.
extern "C" __global__ __launch_bounds__(1024, 1) void minimax_conv_kernel(
    const float* __restrict__ x, const float* __restrict__ w1,
    const float* __restrict__ w2, const int* __restrict__ conn,
    float* __restrict__ out)
{
    extern __shared__ float xs[];

    const int tid = threadIdx.x;
    const int bid = blockIdx.x;
    const int b  = bid >> 4;
    const int r0 = (bid & 15) * 4;

    const float* xb = x + (size_t)b * (CC * HH * WW);

    // ---- stage slab: 6144 float4 chunks = 6 rounds x 1024 threads ----
    // issue all global loads first (single latency exposure), then LDS writes
    float4 tmp[6];
    #pragma unroll
    for (int rnd = 0; rnd < 6; ++rnd) {
        const int f   = rnd * 1024 + tid;        // 16-B chunk id, linear in LDS
        const int c   = f / 96;                  // 96 chunks per channel
        const int rem = f * 4 - c * (HALO * WW); // dword remainder 0..383
        const int rl  = rem >> 6;                // 0..5
        const int col = rem & 63;                // multiple of 4
        int rimg = r0 - 1 + rl;
        rimg = rimg < 0 ? 0 : (rimg > HH - 1 ? HH - 1 : rimg);
        tmp[rnd] = *(const float4*)(xb + (c * HH + rimg) * WW + col);
    }
    #pragma unroll
    for (int rnd = 0; rnd < 6; ++rnd) {
        const int f = rnd * 1024 + tid;
        *(float4*)(xs + f * 4) = tmp[rnd];
    }
    __syncthreads();

    const int lane = tid & 63;                                  // column
    const int Wv   = __builtin_amdgcn_readfirstlane(tid >> 6);  // wave 0..15
    // per-lane clamped columns for kernel col j = 0,1,2 (replicate pad)
    const int colm = (lane == 0)  ? 0  : lane - 1;
    const int colp = (lane == 63) ? 63 : lane + 1;

    // 256 tasks: task = Wv + 16*tt ; o = task&127 (wave-uniform), pp = task>>7
    #pragma unroll 2
    for (int tt = 0; tt < 16; ++tt) {
        const int task = Wv + 16 * tt;
        const int o  = task & 127;
        const int pp = task >> 7;            // row-pair 0/1 -> local rows 2pp+..

        float rA, rB;
        #pragma unroll
        for (int p = 0; p < 3; ++p) {        // branch
            float eA, eB;
            #pragma unroll
            for (int q = 0; q < 3; ++q) {    // tap within branch
                const int t = p * 3 + q;
                const int v = conn[o * 9 + t];        // s_load (uniform)
                const int c = v / 9;
                const int r9 = v - c * 9;
                const int i = r9 / 3;                 // kernel row (uniform)
                const int j = r9 - i * 3;             // kernel col (uniform)
                const float w1v = w1[o * 9 + t];      // uniform

                const int col = (j == 0) ? colm : ((j == 1) ? lane : colp);
                // local rows: 2pp+i and 2pp+i+1 (clamp was baked in at staging)
                const float* pb = xs + c * (HALO * WW) + (2 * pp + i) * WW + col;
                const float gA = pb[0];               // ds_read2_b32 pair
                const float gB = pb[WW];
                const float dA = fabsf(gA - w1v);
                const float dB = fabsf(gB - w1v);
                if (q == 0) { eA = dA; eB = dB; }
                else        { eA = fmaxf(eA, dA); eB = fmaxf(eB, dB); }
            }
            const float w2v = w2[o * 3 + p];          // uniform
            const float mA = fabsf(eA - w2v);
            const float mB = fabsf(eB - w2v);
            if (p == 0) { rA = mA; rB = mB; }
            else        { rA = fminf(rA, mA); rB = fminf(rB, mB); }
        }

        float* ob = out + (((size_t)b * OO + o) * HH + (r0 + 2 * pp)) * WW + lane;
        ob[0]  = rA;
        ob[WW] = rB;
    }
}

extern "C" void kernel_launch(void* const* d_in, const int* in_sizes, int n_in,
                              void* d_out, int out_size, void* d_ws, size_t ws_size,
                              hipStream_t stream) {
    const float* x    = (const float*)d_in[0];
    const float* w1   = (const float*)d_in[1];
    const float* w2   = (const float*)d_in[2];
    const int*   conn = (const int*)d_in[3];
    float* out = (float*)d_out;

    // allow >64 KB dynamic LDS (96 KB slab); idempotent host-side call
    hipFuncSetAttribute((const void*)minimax_conv_kernel,
                        hipFuncAttributeMaxDynamicSharedMemorySize, LDS_BYTES);

    const int blocks = BB * 16;   // (b, row-strip) = 256 = 1 per CU
    minimax_conv_kernel<<<blocks, 1024, LDS_BYTES, stream>>>(x, w1, w2, conn, out);
}